// Round 4
// baseline (760.353 us; speedup 1.0000x reference)
//
#include <hip/hip_runtime.h>

#define NN   50000
#define EE   800000
#define INC  128
#define OUTC 256
#define HALF 128
#define NREL 6
#define NCELL (NN * NREL)   // 300000

typedef __attribute__((ext_vector_type(4))) short s16x4;
typedef __attribute__((ext_vector_type(8))) short bf16x8;
typedef __attribute__((ext_vector_type(4))) float f32x4;

__device__ __forceinline__ float b2f(short b) {
    unsigned u = ((unsigned)(unsigned short)b) << 16;
    return __uint_as_float(u);
}
__device__ __forceinline__ short f2b(float f) {
    unsigned u = __float_as_uint(f);
    unsigned r = (u + 0x7fffu + ((u >> 16) & 1u)) >> 16;   // RNE
    return (short)r;
}

__device__ __forceinline__ void gload16(const void* g, void* l) {
    __builtin_amdgcn_global_load_lds(
        (const __attribute__((address_space(1))) void*)g,
        (__attribute__((address_space(3))) void*)l, 16, 0, 0);
}

// ---------------- CSR build ----------------
__global__ __launch_bounds__(256) void count_k(const int* __restrict__ dst,
                                               const int* __restrict__ et,
                                               int* __restrict__ cnt) {
    int e = blockIdx.x * 256 + threadIdx.x;
    if (e < EE) atomicAdd(&cnt[dst[e] * NREL + et[e]], 1);
}

__global__ __launch_bounds__(256) void scanA_k(const int* __restrict__ cnt,
                                               int* __restrict__ off,
                                               int* __restrict__ bsum, int n) {
    __shared__ int sh[256];
    int t = threadIdx.x;
    int base = blockIdx.x * 512 + t * 2;
    int v0 = (base < n) ? cnt[base] : 0;
    int v1 = (base + 1 < n) ? cnt[base + 1] : 0;
    int s = v0 + v1;
    sh[t] = s; __syncthreads();
    for (int o = 1; o < 256; o <<= 1) {
        int u = (t >= o) ? sh[t - o] : 0;
        __syncthreads();
        sh[t] += u;
        __syncthreads();
    }
    int excl = sh[t] - s;
    if (base < n)     off[base]     = excl;
    if (base + 1 < n) off[base + 1] = excl + v0;
    if (t == 255) bsum[blockIdx.x] = sh[255];
}

__global__ __launch_bounds__(1024) void scanB_k(int* __restrict__ bsum, int nb) {
    __shared__ int sh[1024];
    int t = threadIdx.x;
    int s = (t < nb) ? bsum[t] : 0;
    sh[t] = s; __syncthreads();
    for (int o = 1; o < 1024; o <<= 1) {
        int u = (t >= o) ? sh[t - o] : 0;
        __syncthreads();
        sh[t] += u;
        __syncthreads();
    }
    if (t < nb) bsum[t] = sh[t] - s;
}

__global__ __launch_bounds__(256) void scanC_k(int* __restrict__ off,
                                               const int* __restrict__ bsum, int n) {
    int i = blockIdx.x * 256 + threadIdx.x;
    if (i < n) off[i] += bsum[i >> 9];
    if (i == 0) off[n] = EE;
}

__global__ __launch_bounds__(256) void copyint_k(const int* __restrict__ a,
                                                 int* __restrict__ b, int n) {
    int i = blockIdx.x * 256 + threadIdx.x;
    if (i < n) b[i] = a[i];
}

__global__ __launch_bounds__(256) void fill_k(const int* __restrict__ src,
                                              const int* __restrict__ dst,
                                              const int* __restrict__ et,
                                              int* __restrict__ cur,
                                              int* __restrict__ es) {
    int e = blockIdx.x * 256 + threadIdx.x;
    if (e < EE) {
        int key = dst[e] * NREL + et[e];
        int p = atomicAdd(&cur[key], 1);
        es[p] = src[e];
    }
}

// ---------------- casts ----------------
__global__ __launch_bounds__(256) void cast_x_k(const float* __restrict__ x,
                                                short* __restrict__ xb, int n4) {
    int i = blockIdx.x * 256 + threadIdx.x;
    if (i < n4) {
        float4 v = ((const float4*)x)[i];
        s16x4 o;
        o[0] = f2b(v.x); o[1] = f2b(v.y); o[2] = f2b(v.z); o[3] = f2b(v.w);
        ((s16x4*)xb)[i] = o;
    }
}

// WT[Ncols][Ktot] = [root; W]^T  (bf16)
__global__ __launch_bounds__(256) void wtcat_k(const float* __restrict__ root,
                                               const float* __restrict__ W,
                                               int K0, int Ktot, int Ncols,
                                               short* __restrict__ WT) {
    int i = blockIdx.x * 256 + threadIdx.x;
    if (i >= Ncols * Ktot) return;
    int n = i / Ktot, k = i - n * Ktot;
    float v = (k < K0) ? root[(size_t)k * Ncols + n]
                       : W[(size_t)(k - K0) * Ncols + n];
    WT[(size_t)n * Ktot + k] = f2b(v);
}

// ---------------- per-(node,rel) mean gather into AG [node][rel*D + c] ----------------
template<int D>
__global__ __launch_bounds__(256) void agg_k(const short* __restrict__ X, int ldx,
                                             const int* __restrict__ off,
                                             const int* __restrict__ es,
                                             short* __restrict__ AG, int lda,
                                             int node0, int ncells) {
    constexpr int LPC = D / 4;                 // lanes per cell (32 or 64)
    int sub  = threadIdx.x / LPC;
    int lane = threadIdx.x % LPC;
    int ci = blockIdx.x * (256 / LPC) + sub;
    if (ci >= ncells) return;
    int node = ci / NREL, rel = ci - node * NREL;
    int gcell = (node0 + node) * NREL + rel;
    int beg = off[gcell], end = off[gcell + 1];
    int c0 = lane * 4;
    float s0 = 0.f, s1 = 0.f, s2 = 0.f, s3 = 0.f;
    int j = beg;
    for (; j + 1 < end; j += 2) {
        s16x4 v = *(const s16x4*)(X + (size_t)es[j] * ldx + c0);
        s16x4 w = *(const s16x4*)(X + (size_t)es[j + 1] * ldx + c0);
        s0 += b2f(v[0]) + b2f(w[0]);
        s1 += b2f(v[1]) + b2f(w[1]);
        s2 += b2f(v[2]) + b2f(w[2]);
        s3 += b2f(v[3]) + b2f(w[3]);
    }
    if (j < end) {
        s16x4 v = *(const s16x4*)(X + (size_t)es[j] * ldx + c0);
        s0 += b2f(v[0]); s1 += b2f(v[1]); s2 += b2f(v[2]); s3 += b2f(v[3]);
    }
    float inv = (end > beg) ? 1.f / (float)(end - beg) : 0.f;
    s16x4 o;
    o[0] = f2b(s0 * inv); o[1] = f2b(s1 * inv);
    o[2] = f2b(s2 * inv); o[3] = f2b(s3 * inv);
    *(s16x4*)(AG + (size_t)node * lda + rel * D + c0) = o;
}

// ---------------- bf16 MFMA GEMM, split-A, full-N block, double-buffered ----------------
// C[M,BN] = [A0 | A1] @ BT^T (+bias,+relu).  BM=64, BN=256 or 128, grid (ceil(M/64), 1).
// LDS chunk swizzle: chunk (row R, k-quad q) at slot R*4 + ((q + (R>>1)) & 3):
//   staged slot s holds (r=s>>2, c=((s&3)-(r>>1))&3); a 16-lane b128 read phase hits
//   all 8 bank-groups exactly twice (2-way = free).  Slot order == DMA lane order.
// Pipeline: stage tiles 0,1; per iter: s_waitcnt vmcnt(NDMA) + s_barrier (cur tile
// landed, NDMA newer in flight), ds_read frags, s_barrier, stage tile k+2 into cur's
// buffer, MFMA.  Tail: clamped re-issue (never read), final vmcnt(0) drain before exit.
#define FRD(R, q) ((((R) << 2) + (((q) + ((R) >> 1)) & 3)) * 8)

template<int BN>
__global__ __launch_bounds__(256) void gemm_bt_k(
    const short* __restrict__ A0, int ld0,
    const short* __restrict__ A1, int ld1, int Ksplit,
    const short* __restrict__ BT,
    int M, int K,
    const float* __restrict__ bias, int relu,
    short* __restrict__ Cb, int ldcb,
    float* __restrict__ Cf, int ldcf) {
    constexpr int NBI  = BN / 64;            // B DMA instrs per thread (4 or 2)
    constexpr int NDMA = 1 + NBI;            // DMAs per thread per tile
    constexpr int MT   = (BN == 256) ? 4 : 2;
    __shared__ __align__(16) short As[2][64 * 32];
    __shared__ __align__(16) short Bs[2][BN * 32];

    const int tid = threadIdx.x;
    const int wave = tid >> 6, lane = tid & 63;
    const int l16 = lane & 15, quad = lane >> 4;
    const int wm = (BN == 256) ? 0 : (wave & 1) * 32;
    const int wn = (BN == 256) ? wave * 64 : (wave >> 1) * 64;
    const int bm = blockIdx.x * 64;

    // staging source coords: slot s -> (row s>>2, chunk ((s&3)-(row>>1))&3)
    const int ra = tid >> 2, ca = ((tid & 3) - (ra >> 1)) & 3;
    int rb[NBI], cb[NBI];
    #pragma unroll
    for (int i = 0; i < NBI; ++i) {
        int s = i * 256 + tid;
        rb[i] = s >> 2; cb[i] = ((s & 3) - (rb[i] >> 1)) & 3;
    }

    auto stage = [&](int k0, int b) {
        const short* Ab; int lda; int kk;
        if (k0 < Ksplit) { Ab = A0; lda = ld0; kk = k0; }
        else             { Ab = A1; lda = ld1; kk = k0 - Ksplit; }
        gload16(Ab + (size_t)(bm + ra) * lda + kk + ca * 8,
                &As[b][(wave * 64) * 8]);
        #pragma unroll
        for (int i = 0; i < NBI; ++i)
            gload16(BT + (size_t)rb[i] * K + k0 + cb[i] * 8,
                    &Bs[b][(i * 256 + wave * 64) * 8]);
    };

    float bv[4];
    #pragma unroll
    for (int nt = 0; nt < 4; ++nt) bv[nt] = bias[wn + nt * 16 + l16];

    f32x4 acc[MT][4];
    #pragma unroll
    for (int i = 0; i < MT; ++i)
        #pragma unroll
        for (int j = 0; j < 4; ++j)
            acc[i][j] = (f32x4)0.f;

    const int nIter = K >> 5;
    stage(0, 0);
    stage(32, 1);

    const int klast = (nIter - 1) * 32;
    for (int it = 0; it < nIter; ++it) {
        asm volatile("s_waitcnt vmcnt(%0)\n\ts_barrier" :: "i"(NDMA) : "memory");
        const int b = it & 1;
        bf16x8 af[MT], bf[4];
        #pragma unroll
        for (int mt = 0; mt < MT; ++mt)
            af[mt] = *(const bf16x8*)&As[b][FRD(wm + mt * 16 + l16, quad)];
        #pragma unroll
        for (int nt = 0; nt < 4; ++nt)
            bf[nt] = *(const bf16x8*)&Bs[b][FRD(wn + nt * 16 + l16, quad)];
        asm volatile("s_barrier" ::: "memory");
        int kn = it * 32 + 64;
        stage(kn > klast ? klast : kn, b);
        #pragma unroll
        for (int mt = 0; mt < MT; ++mt)
            #pragma unroll
            for (int nt = 0; nt < 4; ++nt)
                acc[mt][nt] = __builtin_amdgcn_mfma_f32_16x16x32_bf16(
                    af[mt], bf[nt], acc[mt][nt], 0, 0, 0);
    }
    asm volatile("s_waitcnt vmcnt(0)" ::: "memory");

    #pragma unroll
    for (int mt = 0; mt < MT; ++mt) {
        int rb0 = bm + wm + mt * 16 + quad * 4;
        #pragma unroll
        for (int nt = 0; nt < 4; ++nt) {
            int gc = wn + nt * 16 + l16;
            #pragma unroll
            for (int r = 0; r < 4; ++r) {
                int grow = rb0 + r;
                if (grow < M) {
                    float v = acc[mt][nt][r] + bv[nt];
                    if (relu) v = fmaxf(v, 0.f);
                    if (Cb) Cb[(size_t)grow * ldcb + gc] = f2b(v);
                    else    Cf[(size_t)grow * ldcf + gc] = v;
                }
            }
        }
    }
}

// ---------------- host ----------------
extern "C" void kernel_launch(void* const* d_in, const int* in_sizes, int n_in,
                              void* d_out, int out_size, void* d_ws, size_t ws_size,
                              hipStream_t stream) {
    const float* x      = (const float*)d_in[0];
    const int*   ei     = (const int*)d_in[1];
    const int*   srcv   = ei;
    const int*   dstv   = ei + EE;
    const int*   et     = (const int*)d_in[2];
    const float* enc_w0 = (const float*)d_in[3];
    const float* enc_b0 = (const float*)d_in[4];
    const float* enc_w1 = (const float*)d_in[5];
    const float* enc_b1 = (const float*)d_in[6];
    const float* enc_w2 = (const float*)d_in[7];
    const float* enc_b2 = (const float*)d_in[8];
    const float* W1     = (const float*)d_in[9];
    const float* root1  = (const float*)d_in[10];
    const float* b1     = (const float*)d_in[11];
    const float* W2     = (const float*)d_in[12];
    const float* root2  = (const float*)d_in[13];
    const float* b2     = (const float*)d_in[14];
    const float* W3     = (const float*)d_in[15];
    const float* root3  = (const float*)d_in[16];
    const float* b3     = (const float*)d_in[17];
    float* out = (float*)d_out;

    const int NPAD = 50048;                    // 782*64

    char* p = (char*)d_ws;
    auto alloc = [&](size_t bytes) -> char* {
        char* r = p; p += (bytes + 255) & ~(size_t)255; return r;
    };
    short* xb  = (short*)alloc((size_t)NPAD * INC * 2);
    short* g1  = (short*)alloc((size_t)NPAD * OUTC * 2);
    short* g2  = (short*)alloc((size_t)NPAD * OUTC * 2);
    short* WT1 = (short*)alloc((size_t)OUTC * 896 * 2);
    short* WT2 = (short*)alloc((size_t)OUTC * 1792 * 2);
    short* WT3 = (short*)alloc((size_t)HALF * 1792 * 2);
    short* ET0 = (short*)alloc((size_t)OUTC * INC * 2);
    short* ET1 = (short*)alloc((size_t)OUTC * OUTC * 2);
    short* ET2 = (short*)alloc((size_t)HALF * OUTC * 2);
    int* CNT  = (int*)alloc((size_t)NCELL * 4);
    int* OFF  = (int*)alloc((size_t)(NCELL + 1) * 4);
    int* CUR  = (int*)alloc((size_t)NCELL * 4);
    int* ES   = (int*)alloc((size_t)EE * 4);
    int* BSUM = (int*)alloc(1024 * 4);
    size_t fixed = (size_t)(p - (char*)d_ws);

    int chunk = 50000;
    if (fixed + (size_t)50048 * 1536 * 2 > ws_size) chunk = 25000;
    if (chunk == 25000 && fixed + (size_t)25088 * 1536 * 2 > ws_size) chunk = 12500;
    int crpad = ((chunk + 127) / 128) * 128;
    short* AG = (short*)alloc((size_t)crpad * 1536 * 2);

    // ---- CSR build (once; edge structure shared by all 3 layers)
    hipMemsetAsync(CNT, 0, (size_t)NCELL * 4, stream);
    count_k<<<EE / 256, 256, 0, stream>>>(dstv, et, CNT);
    int nbA = (NCELL + 511) / 512;
    scanA_k<<<nbA, 256, 0, stream>>>(CNT, OFF, BSUM, NCELL);
    scanB_k<<<1, 1024, 0, stream>>>(BSUM, nbA);
    scanC_k<<<(NCELL + 255) / 256, 256, 0, stream>>>(OFF, BSUM, NCELL);
    copyint_k<<<(NCELL + 255) / 256, 256, 0, stream>>>(OFF, CUR, NCELL);
    fill_k<<<EE / 256, 256, 0, stream>>>(srcv, dstv, et, CUR, ES);

    // ---- weight transposes + input cast
    cast_x_k<<<(NN * INC / 4 + 255) / 256, 256, 0, stream>>>(x, xb, NN * INC / 4);
    wtcat_k<<<(OUTC * 896 + 255) / 256, 256, 0, stream>>>(root1, W1, INC, 896, OUTC, WT1);
    wtcat_k<<<(OUTC * 1792 + 255) / 256, 256, 0, stream>>>(root2, W2, OUTC, 1792, OUTC, WT2);
    wtcat_k<<<(HALF * 1792 + 255) / 256, 256, 0, stream>>>(root3, W3, OUTC, 1792, HALF, WT3);
    wtcat_k<<<(OUTC * INC + 255) / 256, 256, 0, stream>>>(enc_w0, nullptr, INC, INC, OUTC, ET0);
    wtcat_k<<<(OUTC * OUTC + 255) / 256, 256, 0, stream>>>(enc_w1, nullptr, OUTC, OUTC, OUTC, ET1);
    wtcat_k<<<(HALF * OUTC + 255) / 256, 256, 0, stream>>>(enc_w2, nullptr, OUTC, OUTC, HALF, ET2);

    auto g256 = [&](const short* A0, int ld0, const short* A1, int ld1, int Ksplit,
                    const short* BT, int M, int K, const float* bias, int relu,
                    short* Cb, int ldcb, float* Cf, int ldcf) {
        gemm_bt_k<256><<<dim3((M + 63) / 64, 1), 256, 0, stream>>>(
            A0, ld0, A1, ld1, Ksplit, BT, M, K, bias, relu, Cb, ldcb, Cf, ldcf);
    };
    auto g128 = [&](const short* A0, int ld0, const short* A1, int ld1, int Ksplit,
                    const short* BT, int M, int K, const float* bias, int relu,
                    short* Cb, int ldcb, float* Cf, int ldcf) {
        gemm_bt_k<128><<<dim3((M + 63) / 64, 1), 256, 0, stream>>>(
            A0, ld0, A1, ld1, Ksplit, BT, M, K, bias, relu, Cb, ldcb, Cf, ldcf);
    };

    // ---- encoder -> out[:, 0:128]
    g256(xb, INC, xb, INC, INC, ET0, NN, INC, enc_b0, 1, g1, OUTC, nullptr, 0);
    g256(g1, OUTC, g1, OUTC, OUTC, ET1, NN, OUTC, enc_b1, 1, g2, OUTC, nullptr, 0);
    g128(g2, OUTC, g2, OUTC, OUTC, ET2, NN, OUTC, enc_b2, 0, nullptr, 0, out, OUTC);

    // ---- conv1: xb(128) -> g1
    for (int c0 = 0; c0 < NN; c0 += chunk) {
        int nc = chunk * NREL;
        agg_k<INC><<<(nc + 7) / 8, 256, 0, stream>>>(xb, INC, OFF, ES, AG, 768, c0, nc);
        g256(xb + (size_t)c0 * INC, INC, AG, 768, INC, WT1, chunk, 896,
             b1, 1, g1 + (size_t)c0 * OUTC, OUTC, nullptr, 0);
    }
    // ---- conv2: g1(256) -> g2
    for (int c0 = 0; c0 < NN; c0 += chunk) {
        int nc = chunk * NREL;
        agg_k<OUTC><<<(nc + 3) / 4, 256, 0, stream>>>(g1, OUTC, OFF, ES, AG, 1536, c0, nc);
        g256(g1 + (size_t)c0 * OUTC, OUTC, AG, 1536, OUTC, WT2, chunk, 1792,
             b2, 1, g2 + (size_t)c0 * OUTC, OUTC, nullptr, 0);
    }
    // ---- conv3: g2(256) -> out[:,128:]
    for (int c0 = 0; c0 < NN; c0 += chunk) {
        int nc = chunk * NREL;
        agg_k<OUTC><<<(nc + 3) / 4, 256, 0, stream>>>(g2, OUTC, OFF, ES, AG, 1536, c0, nc);
        g128(g2 + (size_t)c0 * OUTC, OUTC, AG, 1536, OUTC, WT3, chunk, 1792,
             b3, 0, nullptr, 0, out + (size_t)c0 * OUTC + HALF, OUTC);
    }
}